// Round 3
// baseline (1244.353 us; speedup 1.0000x reference)
//
#include <hip/hip_runtime.h>

#define NN 262144
#define KK 1024
#define DD 64
#define DECAY 0.99f
#define ONE_MINUS_DECAY 0.01f
#define EPSF 1e-5f
#define COMMIT 0.25f

// --- precompute 0.5*||c||^2 per code ---------------------------------------
__global__ __launch_bounds__(256) void k_csq(const float* __restrict__ cb,
                                             float* __restrict__ csq_half) {
    int k = blockIdx.x * 256 + threadIdx.x;
    const float4* c4 = (const float4*)(cb + (size_t)k * DD);
    float s = 0.f;
#pragma unroll
    for (int j = 0; j < DD / 4; ++j) {
        float4 c = c4[j];
        s += c.x * c.x + c.y * c.y + c.z * c.z + c.w * c.w;
    }
    csq_half[k] = 0.5f * s;
}

// --- assignment: argmin_k (0.5*||c||^2 - x.c), gather quantized, loss, hist -
// __launch_bounds__(256,2): VGPR cap 256. Rounds 1-2 showed VGPR_Count=64 with
// ~3 VALU issued per useful FMA and no extra memory traffic -> the 64-float
// x-row was parked in AGPRs (unified file) with v_accvgpr_read per use. Grid
// caps occupancy at 16 waves/CU regardless, so a ~128-VGPR allocation costs
// nothing.
__global__ __launch_bounds__(256, 2) void k_assign(
    const float* __restrict__ x, const float* __restrict__ cb,
    const float* __restrict__ csq_half,
    float* __restrict__ quant, int* __restrict__ idx_int,
    int* __restrict__ counts, float* __restrict__ loss_acc)
{
    int i = blockIdx.x * 256 + threadIdx.x;
    float4 xr[16];
    const float4* xrow = (const float4*)(x + (size_t)i * DD);
#pragma unroll
    for (int j = 0; j < 16; ++j) xr[j] = xrow[j];

    float best = 3.4e38f;
    int bestk = 0;
#pragma unroll 2
    for (int k = 0; k < KK; ++k) {
        // k is wave-uniform -> codebook row comes in via s_load on the SMEM
        // pipe; FMAs take the SGPR as one source operand.
        const float4* c4 = (const float4*)(cb + k * DD);
        float a0 = 0.f, a1 = 0.f, a2 = 0.f, a3 = 0.f;
#pragma unroll
        for (int j = 0; j < 16; ++j) {
            float4 c = c4[j];
            a0 += xr[j].x * c.x;
            a1 += xr[j].y * c.y;
            a2 += xr[j].z * c.z;
            a3 += xr[j].w * c.w;
        }
        float dot = (a0 + a1) + (a2 + a3);
        float dp = csq_half[k] - dot;   // argmin proxy (xsq constant per row)
        bool better = dp < best;        // strict < keeps first min (jnp.argmin)
        best  = better ? dp : best;
        bestk = better ? k : bestk;
    }

    idx_int[i] = bestk;
    atomicAdd(&counts[bestk], 1);

    // gather quantized row (codebook is L1/L2-resident) + per-thread sq error
    const float4* q4 = (const float4*)(cb + (size_t)bestk * DD);
    float4* o4 = (float4*)(quant + (size_t)i * DD);
    float err = 0.f;
#pragma unroll
    for (int j = 0; j < 16; ++j) {
        float4 q = q4[j];
        o4[j] = q;
        float ex = q.x - xr[j].x, ey = q.y - xr[j].y;
        float ez = q.z - xr[j].z, ew = q.w - xr[j].w;
        err += ex * ex + ey * ey + ez * ez + ew * ew;
    }
#pragma unroll
    for (int off = 32; off > 0; off >>= 1) err += __shfl_down(err, off);
    if ((threadIdx.x & 63) == 0) atomicAdd(loss_acc, err);
}

// --- single block: EMA cluster size, n-reduce, smoothed, prefix-scan, loss --
__global__ __launch_bounds__(1024) void k_mid(
    const int* __restrict__ counts, const float* __restrict__ ema_cs,
    const float* __restrict__ loss_acc,
    float* __restrict__ new_cs, float* __restrict__ loss_out,
    float* __restrict__ smoothed_inv, int* __restrict__ offsets,
    int* __restrict__ cursor)
{
    int t = threadIdx.x;
    int cnt = counts[t];
    float ncs = DECAY * ema_cs[t] + ONE_MINUS_DECAY * (float)cnt;

    // n = sum(new_cluster_size)
    float s = ncs;
#pragma unroll
    for (int off = 32; off > 0; off >>= 1) s += __shfl_down(s, off);
    __shared__ float wsum[16];
    __shared__ float ntot_s;
    if ((t & 63) == 0) wsum[t >> 6] = s;
    __syncthreads();
    if (t == 0) {
        float tt = 0.f;
        for (int w = 0; w < 16; ++w) tt += wsum[w];
        ntot_s = tt;
    }
    __syncthreads();
    float n = ntot_s;

    float sm = (ncs + EPSF) / (n + (float)KK * EPSF) * n;
    new_cs[t] = ncs;
    smoothed_inv[t] = 1.0f / sm;

    // exclusive scan of counts (Hillis-Steele)
    __shared__ int sc[1024];
    sc[t] = cnt;
    __syncthreads();
    for (int off = 1; off < 1024; off <<= 1) {
        int v = (t >= off) ? sc[t - off] : 0;
        __syncthreads();
        sc[t] += v;
        __syncthreads();
    }
    int excl = sc[t] - cnt;
    offsets[t] = excl;
    cursor[t] = excl;

    if (t == 0) loss_out[0] = COMMIT * loss_acc[0] / (float)(NN * DD);
}

// --- scatter rows into per-code segments; record code per position ---------
__global__ __launch_bounds__(256) void k_scatter(
    int* __restrict__ idx_inout, int* __restrict__ cursor,
    int* __restrict__ perm, int* __restrict__ pcode)
{
    int i = blockIdx.x * 256 + threadIdx.x;
    int k = idx_inout[i];
    int pos = atomicAdd(&cursor[k], 1);
    perm[pos] = i;
    pcode[pos] = k;
    ((float*)idx_inout)[i] = (float)k;   // own-element read happened above
}

// --- balanced segment sum: equal 64-row windows of sorted rows, run-flush ---
__global__ __launch_bounds__(256) void k_segsum(
    const float* __restrict__ x, const int* __restrict__ perm,
    const int* __restrict__ pcode, float* __restrict__ dw)
{
    int w = blockIdx.x * 4 + (threadIdx.x >> 6);  // wave id, 4096 total
    int lane = threadIdx.x & 63;
    int base = w * 64;
    float acc = 0.f;
    int cur = pcode[base];                         // wave-uniform
    for (int r = 0; r < 64; ++r) {
        int c = pcode[base + r];
        if (c != cur) {                            // wave-uniform branch
            atomicAdd(&dw[cur * DD + lane], acc);
            acc = 0.f; cur = c;
        }
        int row = perm[base + r];
        acc += x[(size_t)row * DD + lane];         // 256B coalesced gather
    }
    atomicAdd(&dw[cur * DD + lane], acc);
}

// --- EMA weight update + codebook normalize --------------------------------
__global__ __launch_bounds__(256) void k_final(
    const float* __restrict__ dw, const float* __restrict__ ema_w,
    const float* __restrict__ smoothed_inv,
    float* __restrict__ new_ema_w, float* __restrict__ new_cb)
{
    int i = blockIdx.x * 256 + threadIdx.x;        // K*D = 65536
    int k = i >> 6;
    float nw = DECAY * ema_w[i] + ONE_MINUS_DECAY * dw[i];
    new_ema_w[i] = nw;
    new_cb[i] = nw * smoothed_inv[k];
}

extern "C" void kernel_launch(void* const* d_in, const int* in_sizes, int n_in,
                              void* d_out, int out_size, void* d_ws, size_t ws_size,
                              hipStream_t stream)
{
    const float* x      = (const float*)d_in[0];
    const float* cb     = (const float*)d_in[1];
    const float* ema_cs = (const float*)d_in[2];
    const float* ema_w  = (const float*)d_in[3];

    float* out      = (float*)d_out;
    float* quant    = out;                                   // [N*D]
    float* loss_out = out + (size_t)NN * DD;                 // [1]
    int*   idx_reg  = (int*)(out + (size_t)NN * DD + 1);     // [N] (float slot)
    float* new_cb   = out + (size_t)NN * DD + 1 + NN;        // [K*D]
    float* new_cs   = new_cb + (size_t)KK * DD;              // [K]
    float* new_emaw = new_cs + KK;                           // [K*D]

    char* ws = (char*)d_ws;
    // [loss_acc 256 | counts 4096 | dw 262144]  <- one contiguous memset
    float* loss_acc     = (float*)(ws + 0);
    int*   counts       = (int*)(ws + 256);
    float* dw           = (float*)(ws + 256 + 4096);
    char*  ws2          = ws + 256 + 4096 + 262144;
    int*   offsets      = (int*)(ws2 + 0);
    int*   cursor       = (int*)(ws2 + 4096);
    float* csq_half     = (float*)(ws2 + 8192);
    float* smoothed_inv = (float*)(ws2 + 12288);
    int*   perm         = (int*)(ws2 + 16384);
    int*   pcode        = (int*)(ws2 + 16384 + (size_t)NN * 4);

    hipMemsetAsync(d_ws, 0, 256 + 4096 + 262144, stream);

    k_csq    <<<KK / 256, 256, 0, stream>>>(cb, csq_half);
    k_assign <<<NN / 256, 256, 0, stream>>>(x, cb, csq_half, quant, idx_reg,
                                            counts, loss_acc);
    k_mid    <<<1, 1024, 0, stream>>>(counts, ema_cs, loss_acc, new_cs,
                                      loss_out, smoothed_inv, offsets, cursor);
    k_scatter<<<NN / 256, 256, 0, stream>>>(idx_reg, cursor, perm, pcode);
    k_segsum <<<NN / (256 * 64) , 256, 0, stream>>>(x, perm, pcode, dw);
    k_final  <<<KK * DD / 256, 256, 0, stream>>>(dw, ema_w, smoothed_inv,
                                                 new_emaw, new_cb);
}

// Round 4
// 410.676 us; speedup vs baseline: 3.0300x; 3.0300x over previous
//
#include <hip/hip_runtime.h>

#define NN 262144
#define KK 1024
#define DD 64
#define DECAY 0.99f
#define ONE_MINUS_DECAY 0.01f
#define EPSF 1e-5f
#define COMMIT 0.25f

// padded bf16 codebook planes: 144B per code row (72 bf16, 64 used + 8 pad)
#define ROWB 144
#define CHUNK_CODES 128
#define CHUNK_BYTES (CHUNK_CODES * ROWB * 2)   // hi plane + lo plane = 36864
#define PLANE_BYTES (CHUNK_CODES * ROWB)       // 18432

typedef __bf16 bf16x8 __attribute__((ext_vector_type(8)));
typedef unsigned short ushort8 __attribute__((ext_vector_type(8)));
typedef float float4v __attribute__((ext_vector_type(4)));

__device__ inline unsigned short bf16rne(float f) {
    unsigned int u = __float_as_uint(f);
    u += 0x7fffu + ((u >> 16) & 1u);
    return (unsigned short)(u >> 16);
}

// --- 0.5*||c||^2 per code ---------------------------------------------------
__global__ __launch_bounds__(256) void k_csq(const float* __restrict__ cb,
                                             float* __restrict__ csq_half) {
    int k = blockIdx.x * 256 + threadIdx.x;
    const float4* c4 = (const float4*)(cb + (size_t)k * DD);
    float s = 0.f;
#pragma unroll
    for (int j = 0; j < DD / 4; ++j) {
        float4 c = c4[j];
        s += c.x * c.x + c.y * c.y + c.z * c.z + c.w * c.w;
    }
    csq_half[k] = 0.5f * s;
}

// --- split codebook into chunked, padded bf16 hi/lo planes ------------------
// layout: chunk c (128 codes): [hi: 128*144B][lo: 128*144B], row stride 144B
__global__ __launch_bounds__(256) void k_prep(const float* __restrict__ cb,
                                              unsigned char* __restrict__ cbhl) {
    int e = blockIdx.x * 256 + threadIdx.x;      // 0..65535
    int k = e >> 6, d = e & 63;
    int c = k >> 7, kl = k & 127;
    float f = cb[e];
    unsigned short h = bf16rne(f);
    float hf = __uint_as_float((unsigned int)h << 16);
    unsigned short l = bf16rne(f - hf);
    unsigned char* base = cbhl + (size_t)c * CHUNK_BYTES;
    *(unsigned short*)(base + kl * ROWB + d * 2) = h;
    *(unsigned short*)(base + PLANE_BYTES + kl * ROWB + d * 2) = l;
}

// --- assignment via split-bf16 MFMA + exact top-2 refinement ----------------
// block = 4 waves x 32 rows = 128 rows; wave-tile = 32 rows x 16 codes.
// acc init = 0.5||c||^2, A-frags hold -x (hi/lo) -> acc = csq - x.c after
// 6 MFMA (hi.hi + hi.lo + lo.hi; lo.lo dropped, err ~3e-5, rescued by exact
// fp32 refinement of the per-row top-2 candidates).
__global__ __launch_bounds__(256, 3) void k_assign(
    const float* __restrict__ x, const float* __restrict__ cb,
    const unsigned char* __restrict__ cbhl, const float* __restrict__ csq_half,
    float* __restrict__ quant, int* __restrict__ idx_int,
    int* __restrict__ counts, float* __restrict__ loss_acc)
{
    __shared__ __align__(16) unsigned char ldsbuf[CHUNK_BYTES];

    const int tid  = threadIdx.x;
    const int lane = tid & 63;
    const int wave = tid >> 6;
    const int col  = lane & 15;          // A: m-row sel / B: code sel / C: col
    const int quad = lane >> 4;
    const int rowbase = blockIdx.x * 128 + wave * 32;

    // ---- build negated split-bf16 A fragments for 2 m-tiles x 2 k-halves
    bf16x8 nah[2][2], nal[2][2];
#pragma unroll
    for (int mt = 0; mt < 2; ++mt) {
        const float* xb = x + (size_t)(rowbase + mt * 16 + col) * DD + quad * 8;
#pragma unroll
        for (int kh = 0; kh < 2; ++kh) {
            float4 f0 = *(const float4*)(xb + kh * 32);
            float4 f1 = *(const float4*)(xb + kh * 32 + 4);
            float fv[8] = {f0.x, f0.y, f0.z, f0.w, f1.x, f1.y, f1.z, f1.w};
            ushort8 uh, ul;
#pragma unroll
            for (int j = 0; j < 8; ++j) {
                float nf = -fv[j];
                unsigned short h = bf16rne(nf);
                float hf = __uint_as_float((unsigned int)h << 16);
                uh[j] = h;
                ul[j] = bf16rne(nf - hf);
            }
            nah[mt][kh] = __builtin_bit_cast(bf16x8, uh);
            nal[mt][kh] = __builtin_bit_cast(bf16x8, ul);
        }
    }

    // ---- online top-2 state for 8 rows/lane (2 mtiles x 4 regs)
    float best[8], sec[8];
    int bestk[8], seck[8];
#pragma unroll
    for (int j = 0; j < 8; ++j) { best[j] = 3.4e38f; sec[j] = 3.4e38f; bestk[j] = 0; seck[j] = 0; }

    for (int chunk = 0; chunk < KK / CHUNK_CODES; ++chunk) {
        __syncthreads();
        // stage chunk (hi+lo planes, contiguous 36864B) into LDS
        const uint4* src = (const uint4*)(cbhl + (size_t)chunk * CHUNK_BYTES);
        uint4* dst = (uint4*)ldsbuf;
#pragma unroll
        for (int i = 0; i < CHUNK_BYTES / 16 / 256; ++i)   // 9 iters
            dst[tid + i * 256] = src[tid + i * 256];
        __syncthreads();

        for (int ct = 0; ct < CHUNK_CODES / 16; ++ct) {    // 8 code-tiles
            const int code_local = ct * 16 + col;
            const int codeCol = chunk * CHUNK_CODES + code_local;
            const unsigned char* bp = ldsbuf + code_local * ROWB + quad * 16;
            bf16x8 bh0 = __builtin_bit_cast(bf16x8, *(const uint4*)(bp));
            bf16x8 bh1 = __builtin_bit_cast(bf16x8, *(const uint4*)(bp + 64));
            bf16x8 bl0 = __builtin_bit_cast(bf16x8, *(const uint4*)(bp + PLANE_BYTES));
            bf16x8 bl1 = __builtin_bit_cast(bf16x8, *(const uint4*)(bp + PLANE_BYTES + 64));

            float csq = csq_half[codeCol];
            float4v a0 = {csq, csq, csq, csq};
            float4v a1 = {csq, csq, csq, csq};
            a0 = __builtin_amdgcn_mfma_f32_16x16x32_bf16(nah[0][0], bh0, a0, 0, 0, 0);
            a0 = __builtin_amdgcn_mfma_f32_16x16x32_bf16(nah[0][1], bh1, a0, 0, 0, 0);
            a0 = __builtin_amdgcn_mfma_f32_16x16x32_bf16(nah[0][0], bl0, a0, 0, 0, 0);
            a0 = __builtin_amdgcn_mfma_f32_16x16x32_bf16(nah[0][1], bl1, a0, 0, 0, 0);
            a0 = __builtin_amdgcn_mfma_f32_16x16x32_bf16(nal[0][0], bh0, a0, 0, 0, 0);
            a0 = __builtin_amdgcn_mfma_f32_16x16x32_bf16(nal[0][1], bh1, a0, 0, 0, 0);
            a1 = __builtin_amdgcn_mfma_f32_16x16x32_bf16(nah[1][0], bh0, a1, 0, 0, 0);
            a1 = __builtin_amdgcn_mfma_f32_16x16x32_bf16(nah[1][1], bh1, a1, 0, 0, 0);
            a1 = __builtin_amdgcn_mfma_f32_16x16x32_bf16(nah[1][0], bl0, a1, 0, 0, 0);
            a1 = __builtin_amdgcn_mfma_f32_16x16x32_bf16(nah[1][1], bl1, a1, 0, 0, 0);
            a1 = __builtin_amdgcn_mfma_f32_16x16x32_bf16(nal[1][0], bh0, a1, 0, 0, 0);
            a1 = __builtin_amdgcn_mfma_f32_16x16x32_bf16(nal[1][1], bh1, a1, 0, 0, 0);

#pragma unroll
            for (int r = 0; r < 4; ++r) {
                float dp = a0[r];
                bool c1 = dp < best[r];
                bool c2 = dp < sec[r];
                float ns = c1 ? best[r] : (c2 ? dp : sec[r]);
                int nsk = c1 ? bestk[r] : (c2 ? codeCol : seck[r]);
                best[r] = c1 ? dp : best[r];
                bestk[r] = c1 ? codeCol : bestk[r];
                sec[r] = ns; seck[r] = nsk;
            }
#pragma unroll
            for (int r = 0; r < 4; ++r) {
                float dp = a1[r];
                bool c1 = dp < best[4 + r];
                bool c2 = dp < sec[4 + r];
                float ns = c1 ? best[4 + r] : (c2 ? dp : sec[4 + r]);
                int nsk = c1 ? bestk[4 + r] : (c2 ? codeCol : seck[4 + r]);
                best[4 + r] = c1 ? dp : best[4 + r];
                bestk[4 + r] = c1 ? codeCol : bestk[4 + r];
                sec[4 + r] = ns; seck[4 + r] = nsk;
            }
        }
    }

    // ---- merge top-2 across the 16 col-lanes of each quad (lex by (v,k))
#pragma unroll
    for (int m = 1; m <= 8; m <<= 1) {
#pragma unroll
        for (int j = 0; j < 8; ++j) {
            float ob = __shfl_xor(best[j], m, 16); int obk = __shfl_xor(bestk[j], m, 16);
            float os = __shfl_xor(sec[j],  m, 16); int osk = __shfl_xor(seck[j],  m, 16);
            bool oblt = (ob < best[j]) || (ob == best[j] && obk < bestk[j]);
            float nb  = oblt ? ob  : best[j];
            int  nbk  = oblt ? obk : bestk[j];
            float ca  = oblt ? os  : sec[j];      // winner's own sec
            int  cak  = oblt ? osk : seck[j];
            float cb_ = oblt ? best[j] : ob;      // loser of bests
            int  cbk_ = oblt ? bestk[j] : obk;
            bool alt = (ca < cb_) || (ca == cb_ && cak < cbk_);
            best[j] = nb; bestk[j] = nbk;
            sec[j]  = alt ? ca  : cb_;
            seck[j] = alt ? cak : cbk_;
        }
    }

    // ---- stash (k1,k2) per row in LDS (reuse staging buffer)
    __syncthreads();
    int2* scratch = (int2*)ldsbuf;
    if (col == 0) {
#pragma unroll
        for (int j = 0; j < 8; ++j) {
            int row_local = (j >> 2) * 16 + quad * 4 + (j & 3);
            scratch[wave * 32 + row_local] = make_int2(bestk[j], seck[j]);
        }
    }
    __syncthreads();

    // ---- exact fp32 refinement: 2 lanes per row (dim halves)
    const int r = lane >> 1;              // 0..31 local row
    const int h = lane & 1;               // dim half
    const int grow = rowbase + r;
    int2 kk = scratch[wave * 32 + r];
    const float4* xh = (const float4*)(x + (size_t)grow * DD + h * 32);
    float4 xr4[8];
#pragma unroll
    for (int j = 0; j < 8; ++j) xr4[j] = xh[j];

    float p1 = 0.f, p2 = 0.f;
    const float4* c1p = (const float4*)(cb + (size_t)kk.x * DD + h * 32);
    const float4* c2p = (const float4*)(cb + (size_t)kk.y * DD + h * 32);
#pragma unroll
    for (int j = 0; j < 8; ++j) {
        float4 c1 = c1p[j], c2 = c2p[j];
        p1 += xr4[j].x * c1.x + xr4[j].y * c1.y + xr4[j].z * c1.z + xr4[j].w * c1.w;
        p2 += xr4[j].x * c2.x + xr4[j].y * c2.y + xr4[j].z * c2.z + xr4[j].w * c2.w;
    }
    float d1 = csq_half[kk.x] - (p1 + __shfl_xor(p1, 1));
    float d2 = csq_half[kk.y] - (p2 + __shfl_xor(p2, 1));
    bool pick1 = (d1 < d2) || (d1 == d2 && kk.x < kk.y);
    int w = pick1 ? kk.x : kk.y;

    // gather winner row, write quantized, accumulate loss
    const float4* qp = (const float4*)(cb + (size_t)w * DD + h * 32);
    float4* op = (float4*)(quant + (size_t)grow * DD + h * 32);
    float err = 0.f;
#pragma unroll
    for (int j = 0; j < 8; ++j) {
        float4 q = qp[j];
        op[j] = q;
        float ex = q.x - xr4[j].x, ey = q.y - xr4[j].y;
        float ez = q.z - xr4[j].z, ew = q.w - xr4[j].w;
        err += ex * ex + ey * ey + ez * ez + ew * ew;
    }
#pragma unroll
    for (int off = 32; off > 0; off >>= 1) err += __shfl_down(err, off);
    if (lane == 0) atomicAdd(loss_acc, err);
    if (h == 0) {
        idx_int[grow] = w;
        atomicAdd(&counts[w], 1);
    }
}

// --- single block: EMA cluster size, n-reduce, smoothed, scan, loss ---------
__global__ __launch_bounds__(1024) void k_mid(
    const int* __restrict__ counts, const float* __restrict__ ema_cs,
    const float* __restrict__ loss_acc,
    float* __restrict__ new_cs, float* __restrict__ loss_out,
    float* __restrict__ smoothed_inv, int* __restrict__ offsets,
    int* __restrict__ cursor)
{
    int t = threadIdx.x; int lane = t & 63; int w = t >> 6;
    int cnt = counts[t];
    float ncs = DECAY * ema_cs[t] + ONE_MINUS_DECAY * (float)cnt;

    __shared__ float wsumf[16];
    __shared__ int wsumi[16];
    __shared__ float ntot_s;

    float s = ncs;
#pragma unroll
    for (int off = 32; off > 0; off >>= 1) s += __shfl_down(s, off);
    if (lane == 0) wsumf[w] = s;

    // intra-wave inclusive scan of counts
    int v = cnt;
#pragma unroll
    for (int off = 1; off < 64; off <<= 1) {
        int u = __shfl_up(v, off);
        if (lane >= off) v += u;
    }
    if (lane == 63) wsumi[w] = v;
    __syncthreads();
    if (t == 0) {
        float tt = 0.f;
        for (int i = 0; i < 16; ++i) tt += wsumf[i];
        ntot_s = tt;
    }
    if (w == 0 && lane < 16) {
        int u = wsumi[lane]; int vv = u;
#pragma unroll
        for (int off = 1; off < 16; off <<= 1) {
            int p = __shfl_up(vv, off, 16);
            if ((lane & 15) >= off) vv += p;
        }
        wsumi[lane] = vv - u;      // exclusive wave offsets
    }
    __syncthreads();
    float n = ntot_s;

    float sm = (ncs + EPSF) / (n + (float)KK * EPSF) * n;
    new_cs[t] = ncs;
    smoothed_inv[t] = 1.0f / sm;

    int excl = wsumi[w] + v - cnt;
    offsets[t] = excl;
    cursor[t] = excl;

    if (t == 0) loss_out[0] = COMMIT * loss_acc[0] / (float)(NN * DD);
}

// --- scatter rows into per-code segments; record code per position ---------
__global__ __launch_bounds__(256) void k_scatter(
    int* __restrict__ idx_inout, int* __restrict__ cursor,
    int* __restrict__ perm, int* __restrict__ pcode)
{
    int i = blockIdx.x * 256 + threadIdx.x;
    int k = idx_inout[i];
    int pos = atomicAdd(&cursor[k], 1);
    perm[pos] = i;
    pcode[pos] = k;
    ((float*)idx_inout)[i] = (float)k;   // own-element read happened above
}

// --- balanced segment sum over sorted rows ----------------------------------
__global__ __launch_bounds__(256) void k_segsum(
    const float* __restrict__ x, const int* __restrict__ perm,
    const int* __restrict__ pcode, float* __restrict__ dw)
{
    int w = blockIdx.x * 4 + (threadIdx.x >> 6);
    int lane = threadIdx.x & 63;
    int base = w * 64;
    float acc = 0.f;
    int cur = pcode[base];
    for (int r = 0; r < 64; ++r) {
        int c = pcode[base + r];
        if (c != cur) {
            atomicAdd(&dw[cur * DD + lane], acc);
            acc = 0.f; cur = c;
        }
        int row = perm[base + r];
        acc += x[(size_t)row * DD + lane];
    }
    atomicAdd(&dw[cur * DD + lane], acc);
}

// --- EMA weight update + codebook normalize --------------------------------
__global__ __launch_bounds__(256) void k_final(
    const float* __restrict__ dw, const float* __restrict__ ema_w,
    const float* __restrict__ smoothed_inv,
    float* __restrict__ new_ema_w, float* __restrict__ new_cb)
{
    int i = blockIdx.x * 256 + threadIdx.x;
    int k = i >> 6;
    float nw = DECAY * ema_w[i] + ONE_MINUS_DECAY * dw[i];
    new_ema_w[i] = nw;
    new_cb[i] = nw * smoothed_inv[k];
}

extern "C" void kernel_launch(void* const* d_in, const int* in_sizes, int n_in,
                              void* d_out, int out_size, void* d_ws, size_t ws_size,
                              hipStream_t stream)
{
    const float* x      = (const float*)d_in[0];
    const float* cb     = (const float*)d_in[1];
    const float* ema_cs = (const float*)d_in[2];
    const float* ema_w  = (const float*)d_in[3];

    float* out      = (float*)d_out;
    float* quant    = out;                                   // [N*D]
    float* loss_out = out + (size_t)NN * DD;                 // [1]
    int*   idx_reg  = (int*)(out + (size_t)NN * DD + 1);     // [N] (float slot)
    float* new_cb   = out + (size_t)NN * DD + 1 + NN;        // [K*D]
    float* new_cs   = new_cb + (size_t)KK * DD;              // [K]
    float* new_emaw = new_cs + KK;                           // [K*D]

    char* ws = (char*)d_ws;
    float* loss_acc     = (float*)(ws + 0);                  // 256 B
    int*   counts       = (int*)(ws + 256);                  // 4 KB
    float* dw           = (float*)(ws + 4352);               // 256 KB
    int*   offsets      = (int*)(ws + 266496);               // 4 KB
    int*   cursor       = (int*)(ws + 270592);               // 4 KB
    float* csq_half     = (float*)(ws + 274688);             // 4 KB
    float* smoothed_inv = (float*)(ws + 278784);             // 4 KB
    unsigned char* cbhl = (unsigned char*)(ws + 282880);     // 288 KB
    int*   perm         = (int*)(ws + 577792);               // 1 MB
    int*   pcode        = (int*)(ws + 1626368);              // 1 MB

    hipMemsetAsync(d_ws, 0, 266496, stream);   // loss_acc + counts + dw

    k_csq    <<<KK / 256, 256, 0, stream>>>(cb, csq_half);
    k_prep   <<<KK * DD / 256, 256, 0, stream>>>(cb, cbhl);
    k_assign <<<NN / 128, 256, 0, stream>>>(x, cb, cbhl, csq_half, quant,
                                            idx_reg, counts, loss_acc);
    k_mid    <<<1, 1024, 0, stream>>>(counts, ema_cs, loss_acc, new_cs,
                                      loss_out, smoothed_inv, offsets, cursor);
    k_scatter<<<NN / 256, 256, 0, stream>>>(idx_reg, cursor, perm, pcode);
    k_segsum <<<NN / (256 * 64), 256, 0, stream>>>(x, perm, pcode, dw);
    k_final  <<<KK * DD / 256, 256, 0, stream>>>(dw, ema_w, smoothed_inv,
                                                 new_emaw, new_cb);
}